// Round 12
// baseline (258.168 us; speedup 1.0000x reference)
//
#include <hip/hip_runtime.h>
#include <math.h>

// N=50000 nodes, E0=800000 edges (+N self loops), IN=128, H=8, C=8 (HC=64), ED=16, T=96
// Node data lives in ONE interleaved 768B record per node (6 cache lines):
//   ushort offsets: kb 0-63 | Gb 64-191 | vb 192-255 | tpn 256-351 | an(f32) 352-367 | bn(f32) 368-383
// Projections via one MFMA GEMM x[N][128] @ B[128][336]; edge phase fused per-node
// (chunked online softmax, all-register, two-stage load/compute pipeline).

struct __align__(8) US4 { unsigned short x, y, z, w; };

typedef __attribute__((ext_vector_type(8))) short bf16x8;
typedef __attribute__((ext_vector_type(4))) float f32x4;

#define CH 32

__device__ __forceinline__ unsigned short f2bf(float f) {
    unsigned u = __float_as_uint(f);
    unsigned r = (u + 0x7fffu + ((u >> 16) & 1u)) >> 16;
    return (unsigned short)r;
}
__device__ __forceinline__ float bf2f(unsigned short u) {
    return __uint_as_float(((unsigned)u) << 16);
}
__device__ __forceinline__ float blo(unsigned u) { return __uint_as_float(u << 16); }
__device__ __forceinline__ float bhi(unsigned u) { return __uint_as_float(u & 0xffff0000u); }

// ---------------- pack B fragments: Bp[((t*4+s)*64+lane)*8+i] ----------------
__global__ __launch_bounds__(256) void k_bpack(
    const float* __restrict__ Wq, const float* __restrict__ Wk, const float* __restrict__ Wv,
    const float* __restrict__ compW, const float* __restrict__ We,
    unsigned short* __restrict__ Bp)
{
    int gid = blockIdx.x * 256 + threadIdx.x;
    if (gid >= 21 * 2048) return;                 // 43008
    int i = gid & 7, lane = (gid >> 3) & 63, s = (gid >> 9) & 3, t = gid >> 11;
    int col = t * 16 + (lane & 15);
    int k = s * 32 + ((lane >> 4) << 3) + i;
    float v;
    if (col < 64)        v = Wq[col * 128 + k];
    else if (col < 128)  v = Wk[(col - 64) * 128 + k];
    else if (col < 192)  v = Wv[(col - 128) * 128 + k];
    else if (col < 200)  v = compW[(col - 192) * 256 + k];
    else if (col < 208)  v = compW[(col - 200) * 256 + 128 + k];
    else {
        int hd = col - 208, h = hd >> 4, d = hd & 15;
        v = 0.f;
        #pragma unroll
        for (int c = 0; c < 8; c++)
            v += Wk[(h * 8 + c) * 128 + k] * We[(h * 8 + c) * 16 + d];
    }
    Bp[gid] = f2bf(v);
}

__device__ __forceinline__ bf16x8 ld_bf8(const float* p) {
    float4 a = ((const float4*)p)[0], b = ((const float4*)p)[1];
    bf16x8 r;
    r[0] = (short)f2bf(a.x); r[1] = (short)f2bf(a.y);
    r[2] = (short)f2bf(a.z); r[3] = (short)f2bf(a.w);
    r[4] = (short)f2bf(b.x); r[5] = (short)f2bf(b.y);
    r[6] = (short)f2bf(b.z); r[7] = (short)f2bf(b.w);
    return r;
}

// ---------------- MFMA projection GEMM -> q (separate) + interleaved record ----------------
__global__ __launch_bounds__(256) void k_gemm(
    const float* __restrict__ x, const unsigned short* __restrict__ Bp,
    const float* __restrict__ compb,
    float* __restrict__ q, unsigned short* __restrict__ rec, int N)
{
    const int tid = threadIdx.x, w = tid >> 6, lane = tid & 63;
    const int half = lane >> 4;                   // 0..3
    const int c0 = lane & 15;
    int row_a = blockIdx.x * 64 + w * 16 + c0;
    int ra = min(row_a, N - 1);
    const float* xr = x + (size_t)ra * 128 + half * 8;
    bf16x8 a0 = ld_bf8(xr +  0);
    bf16x8 a1 = ld_bf8(xr + 32);
    bf16x8 a2 = ld_bf8(xr + 64);
    bf16x8 a3 = ld_bf8(xr + 96);
    const int rbase = blockIdx.x * 64 + w * 16 + half * 4;
    const float cbv = compb[c0 & 7];

    for (int t = 0; t < 21; t++) {
        f32x4 acc = {0.f, 0.f, 0.f, 0.f};
        const bf16x8* bp = (const bf16x8*)(Bp + (size_t)((t * 4) * 64 + lane) * 8);
        acc = __builtin_amdgcn_mfma_f32_16x16x32_bf16(a0, bp[0],   acc, 0, 0, 0);
        acc = __builtin_amdgcn_mfma_f32_16x16x32_bf16(a1, bp[64],  acc, 0, 0, 0);
        acc = __builtin_amdgcn_mfma_f32_16x16x32_bf16(a2, bp[128], acc, 0, 0, 0);
        acc = __builtin_amdgcn_mfma_f32_16x16x32_bf16(a3, bp[192], acc, 0, 0, 0);
        #pragma unroll
        for (int r = 0; r < 4; r++) {
            int rr = rbase + r;
            if (rr >= N) continue;
            float vr = acc[r];
            unsigned short* recR = rec + (size_t)rr * 384;
            if (t < 4)        q[(size_t)rr * 64 + t * 16 + c0] = vr * 0.35355339059327373f;
            else if (t < 8)   recR[(t - 4) * 16 + c0] = f2bf(vr);            // kb
            else if (t < 12)  recR[192 + (t - 8) * 16 + c0] = f2bf(vr);      // vb
            else if (t == 12) {
                if (c0 < 8) ((float*)(recR + 352))[c0] = vr;                 // an
                else        ((float*)(recR + 368))[c0 - 8] = vr + cbv;       // bn (+comp_b)
            }
            else              recR[64 + (t - 13) * 16 + c0] = f2bf(vr);      // Gb
        }
    }
}

// ---------------- tpn (ddof=1) -> bf16 into record, one wave per node ----------
__global__ __launch_bounds__(256) void k_tpn(const float* __restrict__ tp,
                                             unsigned short* __restrict__ rec, int N)
{
    int wave = threadIdx.x >> 6;
    int lane = threadIdx.x & 63;
    int n = blockIdx.x * 4 + wave;
    if (n >= N) return;
    const float* row = tp + (size_t)n * 96;
    float v0 = row[lane];
    float v1 = (lane < 32) ? row[64 + lane] : 0.f;
    float s = v0 + v1, ss = v0 * v0 + v1 * v1;
    #pragma unroll
    for (int m = 1; m < 64; m <<= 1) { s += __shfl_xor(s, m); ss += __shfl_xor(ss, m); }
    float mean = s * (1.f / 96.f);
    float var = (ss - 96.f * mean * mean) * (1.f / 95.f);
    var = fmaxf(var, 0.f);
    float inv = 1.f / (sqrtf(var) + 1e-8f);
    unsigned short* orow = rec + (size_t)n * 384 + 256;
    orow[lane] = f2bf((v0 - mean) * inv);
    if (lane < 32) orow[64 + lane] = f2bf((v1 - mean) * inv);
}

// ---------------- CSR build: histogram(+rank) / 3-stage scan / atomic-free scatter ----------
__global__ __launch_bounds__(256) void k_hist(const int* __restrict__ ei,
                                              int* __restrict__ deg,
                                              int* __restrict__ rnk, int E0, int N)
{
    int e = blockIdx.x * 256 + threadIdx.x;
    int E = E0 + N;
    if (e >= E) return;
    int dst = (e < E0) ? ei[E0 + e] : (e - E0);
    rnk[e] = atomicAdd(&deg[dst], 1);
}

__global__ __launch_bounds__(256) void k_scanA(const int* __restrict__ deg,
                                               int* __restrict__ bsum, int N)
{
    __shared__ int sm[256];
    int i = blockIdx.x * 256 + threadIdx.x;
    sm[threadIdx.x] = (i < N) ? deg[i] : 0;
    __syncthreads();
    for (int off = 128; off > 0; off >>= 1) {
        if (threadIdx.x < off) sm[threadIdx.x] += sm[threadIdx.x + off];
        __syncthreads();
    }
    if (threadIdx.x == 0) bsum[blockIdx.x] = sm[0];
}

__global__ __launch_bounds__(256) void k_scanB(int* __restrict__ bsum, int NB)
{
    __shared__ int sm[256];
    int t = threadIdx.x;
    sm[t] = (t < NB) ? bsum[t] : 0;
    __syncthreads();
    for (int off = 1; off < 256; off <<= 1) {
        int v = (t >= off) ? sm[t - off] : 0;
        __syncthreads();
        sm[t] += v;
        __syncthreads();
    }
    if (t < NB) bsum[t] = (t == 0) ? 0 : sm[t - 1];
}

__global__ __launch_bounds__(256) void k_scanC(const int* __restrict__ deg,
                                               const int* __restrict__ bsum,
                                               int* __restrict__ row, int N)
{
    __shared__ int sm[256];
    int b = blockIdx.x, t = threadIdx.x, i = b * 256 + t;
    int v = (i < N) ? deg[i] : 0;
    sm[t] = v;
    __syncthreads();
    for (int off = 1; off < 256; off <<= 1) {
        int u = (t >= off) ? sm[t - off] : 0;
        __syncthreads();
        sm[t] += u;
        __syncthreads();
    }
    int excl = bsum[b] + sm[t] - v;
    if (i < N) {
        row[i] = excl;
        if (i == N - 1) row[N] = excl + v;
    }
}

__global__ __launch_bounds__(256) void k_scatter(const int* __restrict__ ei,
                                                 const int* __restrict__ row,
                                                 const int* __restrict__ rnk,
                                                 int2* __restrict__ csrd, int E0, int N)
{
    int e = blockIdx.x * 256 + threadIdx.x;
    int E = E0 + N;
    if (e >= E) return;
    int src, dst;
    if (e < E0) { src = ei[e]; dst = ei[E0 + e]; }
    else        { src = e - E0; dst = src; }
    int pos = row[dst] + rnk[e];
    csrd[pos] = make_int2(e, src);
}

// ---------------- fused per-node attention: two-stage load/compute pipeline ----------
// one wave per node (4/block). lane = g*8+h: group g = edge slot, h = head / channel block.
// Load stage issues ALL chunk gathers into registers, compute stage is pure ALU.
__global__ __launch_bounds__(256) void k_nodeattn(
    const int2* __restrict__ csrd, const int* __restrict__ row,
    const float* __restrict__ eattr,
    const float* __restrict__ q, const unsigned short* __restrict__ rec,
    const float* __restrict__ Wo, const float* __restrict__ bo,
    float* __restrict__ out, int E0, int N)
{
    const int tid = threadIdx.x;
    const int wave = tid >> 6, lane = tid & 63;
    const int n = blockIdx.x * 4 + wave;
    if (n >= N) return;

    const int beg = row[n], end = row[n + 1];
    const int h = lane & 7;           // head / channel block
    const int g = lane >> 3;          // edge slot
    const int koff = h * 8;           // per-lane record offsets (ushorts)
    const int goff = 64 + h * 16;
    const int voff = 192 + h * 8;
    const int toff = 256 + h * 12;

    // hoisted dst-side data (per head h) from own record
    const unsigned short* recN = rec + (size_t)n * 384;
    const float4* qp = (const float4*)(q + (size_t)n * 64 + h * 8);
    const float4 qd0 = qp[0], qd1 = qp[1];
    const uint2* tdp = (const uint2*)(recN + toff);
    const uint2 td0 = tdp[0], td1 = tdp[1], td2 = tdp[2];
    const float bnh = ((const float*)(recN + 368))[h];

    float m_reg = -1e30f, dsum = 0.f;
    float acc[8];
    #pragma unroll
    for (int c = 0; c < 8; c++) acc[c] = 0.f;

    for (int cbeg = beg; cbeg < end; cbeg += CH) {
        const int cnt = min(CH, end - cbeg);
        const int last = cnt - 1;

        int2 es[4];
        US4  kk0[4], kk1[4];
        uint4 gg0[4], gg1[4];
        uint4 vv[4];
        float aa[4];
        uint2 tt0[4], tt1[4], tt2[4];

        // ---- load stage 1: csrd entries (clamped within active rows) ----
        #pragma unroll
        for (int j = 0; j < 4; j++) {
            if (8 * j < cnt) {                      // wave-uniform row guard
                es[j] = csrd[cbeg + min(g + 8 * j, last)];
            }
        }
        // ---- load stage 2: all record gathers for the chunk ----
        #pragma unroll
        for (int j = 0; j < 4; j++) {
            if (8 * j < cnt) {
                const unsigned short* recS = rec + (size_t)es[j].y * 384;
                vv[j]  = *(const uint4*)(recS + voff);
                const US4* kp = (const US4*)(recS + koff);
                kk0[j] = kp[0]; kk1[j] = kp[1];
                const uint4* gp = (const uint4*)(recS + goff);
                gg0[j] = gp[0]; gg1[j] = gp[1];
                aa[j]  = ((const float*)(recS + 352))[h];
                const uint2* tsp = (const uint2*)(recS + toff);
                tt0[j] = tsp[0]; tt1[j] = tsp[1]; tt2[j] = tsp[2];
            }
        }

        // ---- compute stage ----
        float av[4];
        #pragma unroll
        for (int j = 0; j < 4; j++) {
            av[j] = -1e30f;
            if (8 * j < cnt) {
                const int e = es[j].x;
                US4 k0 = kk0[j], k1 = kk1[j];
                float qk = qd0.x*bf2f(k0.x) + qd0.y*bf2f(k0.y) + qd0.z*bf2f(k0.z) + qd0.w*bf2f(k0.w)
                         + qd1.x*bf2f(k1.x) + qd1.y*bf2f(k1.y) + qd1.z*bf2f(k1.z) + qd1.w*bf2f(k1.w);

                uint4 g0 = gg0[j], g1 = gg1[j];
                int ec = (e < E0) ? e : 0;
                const float4* ep4 = (const float4*)(eattr + (size_t)ec * 16);
                float4 e0 = ep4[0], e1 = ep4[1], e2 = ep4[2], e3 = ep4[3];
                if (e >= E0) {
                    e0 = make_float4(1.f, 1.f, 1.f, 1.f); e1 = e0; e2 = e0; e3 = e0;
                }
                float efk = e0.x*blo(g0.x) + e0.y*bhi(g0.x) + e0.z*blo(g0.y) + e0.w*bhi(g0.y)
                          + e1.x*blo(g0.z) + e1.y*bhi(g0.z) + e1.z*blo(g0.w) + e1.w*bhi(g0.w)
                          + e2.x*blo(g1.x) + e2.y*bhi(g1.x) + e2.z*blo(g1.y) + e2.w*bhi(g1.y)
                          + e3.x*blo(g1.z) + e3.y*bhi(g1.z) + e3.z*blo(g1.w) + e3.w*bhi(g1.w);

                float tv = aa[j] + bnh;
                float ex = __expf(2.f * tv);
                float tn = 1.f - 2.f / (ex + 1.f);

                uint2 s0 = tt0[j], s1 = tt1[j], s2 = tt2[j];
                float pc = blo(s0.x)*blo(td0.x) + bhi(s0.x)*bhi(td0.x)
                         + blo(s0.y)*blo(td0.y) + bhi(s0.y)*bhi(td0.y)
                         + blo(s1.x)*blo(td1.x) + bhi(s1.x)*bhi(td1.x)
                         + blo(s1.y)*blo(td1.y) + bhi(s1.y)*bhi(td1.y)
                         + blo(s2.x)*blo(td2.x) + bhi(s2.x)*bhi(td2.x)
                         + blo(s2.y)*blo(td2.y) + bhi(s2.y)*bhi(td2.y);
                float cv = pc * (-0.25f / 96.f) + tn * (-0.25f / 8.f);
                cv += __shfl_xor(cv, 1); cv += __shfl_xor(cv, 2); cv += __shfl_xor(cv, 4);

                float a = qk + efk + cv;
                a = fmaxf(a, 0.2f * a);                // leaky relu
                if (g + 8 * j < cnt) av[j] = a;        // discard clamped duplicates
            }
        }

        // ---- chunk max per head (across groups: lane bits 3-5) ----
        float mloc = fmaxf(fmaxf(av[0], av[1]), fmaxf(av[2], av[3]));
        mloc = fmaxf(mloc, __shfl_xor(mloc, 8));
        mloc = fmaxf(mloc, __shfl_xor(mloc, 16));
        mloc = fmaxf(mloc, __shfl_xor(mloc, 32));

        // ---- online merge + accumulate (all register) ----
        float mn = fmaxf(m_reg, mloc);
        float sc = __expf(m_reg - mn);
        m_reg = mn;
        dsum *= sc;
        #pragma unroll
        for (int c = 0; c < 8; c++) acc[c] *= sc;

        #pragma unroll
        for (int j = 0; j < 4; j++) {
            if (8 * j < cnt) {                       // wave-uniform row guard
                float p = __expf(av[j] - mn);        // 0 for clamped/inactive slots
                dsum += p;
                acc[0] += p * blo(vv[j].x); acc[1] += p * bhi(vv[j].x);
                acc[2] += p * blo(vv[j].y); acc[3] += p * bhi(vv[j].y);
                acc[4] += p * blo(vv[j].z); acc[5] += p * bhi(vv[j].z);
                acc[6] += p * blo(vv[j].w); acc[7] += p * bhi(vv[j].w);
            }
        }
    }

    // ---- merge slots (bits 3-5): per-head denom + channel sums ----
    dsum += __shfl_xor(dsum, 8); dsum += __shfl_xor(dsum, 16); dsum += __shfl_xor(dsum, 32);
    #pragma unroll
    for (int c = 0; c < 8; c++) {
        acc[c] += __shfl_xor(acc[c], 8);
        acc[c] += __shfl_xor(acc[c], 16);
        acc[c] += __shfl_xor(acc[c], 32);
    }
    float inv = 1.f / (dsum + 1e-16f);

    // ---- fused Wo projection: lane holds channels h*8..h*8+7 ----
    float po[8];
    #pragma unroll
    for (int cp8 = 0; cp8 < 8; cp8++) {
        const float4* wr = (const float4*)(Wo + cp8 * 64 + h * 8);
        float4 w0 = wr[0], w1 = wr[1];
        po[cp8] = inv * (acc[0]*w0.x + acc[1]*w0.y + acc[2]*w0.z + acc[3]*w0.w
                       + acc[4]*w1.x + acc[5]*w1.y + acc[6]*w1.z + acc[7]*w1.w);
    }
    #pragma unroll
    for (int cp8 = 0; cp8 < 8; cp8++) {
        po[cp8] += __shfl_xor(po[cp8], 1);
        po[cp8] += __shfl_xor(po[cp8], 2);
        po[cp8] += __shfl_xor(po[cp8], 4);
    }
    if (lane < 8) out[(size_t)n * 8 + lane] = po[lane] + bo[lane];
}

extern "C" void kernel_launch(void* const* d_in, const int* in_sizes, int n_in,
                              void* d_out, int out_size, void* d_ws, size_t ws_size,
                              hipStream_t stream)
{
    const float* x     = (const float*)d_in[0];
    const int*   ei    = (const int*)d_in[1];
    const float* eattr = (const float*)d_in[2];
    const float* tp    = (const float*)d_in[3];
    const float* Wq    = (const float*)d_in[4];
    const float* Wk    = (const float*)d_in[5];
    const float* Wv    = (const float*)d_in[6];
    const float* We    = (const float*)d_in[7];
    const float* compW = (const float*)d_in[8];
    const float* compb = (const float*)d_in[9];
    const float* Wo    = (const float*)d_in[10];
    const float* bo    = (const float*)d_in[11];
    float* out = (float*)d_out;

    const int N  = in_sizes[0] / 128;
    const int E0 = in_sizes[1] / 2;
    const int E  = E0 + N;
    const int NB = (N + 255) / 256;

    float* ws = (float*)d_ws;
    size_t off = 0;
    unsigned short* rec = (unsigned short*)(ws + off); off += (size_t)N * 192;   // N x 768B records
    float* q  = ws + off; off += (size_t)N * 64;
    int* deg    = (int*)(ws + off); off += N;
    int* bsum   = (int*)(ws + off); off += 256;
    int* rowp   = (int*)(ws + off); off += N + 4;
    unsigned short* Bp = (unsigned short*)(ws + off); off += 21504;              // 43008 ushort
    int2* csrd  = (int2*)(ws + off); off += (size_t)E * 2;
    int* rnk    = (int*)(ws + off); off += E;

    hipMemsetAsync(deg, 0, (size_t)N * sizeof(int), stream);

    k_hist<<<(E + 255) / 256, 256, 0, stream>>>(ei, deg, rnk, E0, N);
    k_scanA<<<NB, 256, 0, stream>>>(deg, bsum, N);
    k_scanB<<<1, 256, 0, stream>>>(bsum, NB);
    k_scanC<<<NB, 256, 0, stream>>>(deg, bsum, rowp, N);
    k_scatter<<<(E + 255) / 256, 256, 0, stream>>>(ei, rowp, rnk, csrd, E0, N);

    k_bpack<<<(21 * 2048 + 255) / 256, 256, 0, stream>>>(Wq, Wk, Wv, compW, We, Bp);
    k_gemm<<<(N + 63) / 64, 256, 0, stream>>>(x, Bp, compb, q, rec, N);
    k_tpn<<<(N + 3) / 4, 256, 0, stream>>>(tp, rec, N);

    k_nodeattn<<<(N + 3) / 4, 256, 0, stream>>>(csrd, rowp, eattr, q, rec,
                                                Wo, bo, out, E0, N);
}

// Round 13
// 207.233 us; speedup vs baseline: 1.2458x; 1.2458x over previous
//
#include <hip/hip_runtime.h>
#include <math.h>

// N=50000 nodes, E0=800000 edges (+N self loops), IN=128, H=8, C=8 (HC=64), ED=16, T=96
// Node data: ONE interleaved 640B record per node (exactly 5 cache lines):
//   bytes: kb 0-127 | Gb 128-383 | vb 384-511 | tpn(int8, scale 12) 512-607 | an(f32) 608-639
//   (bn lives in a separate dst-side array; q separate f32, pre-scaled 1/sqrt8)
// Projections via one MFMA GEMM x[N][128] @ B[128][336]; edge phase fused per-node
// (chunked online softmax, all-register, r11-proven inline-load structure).

struct __align__(8) US4 { unsigned short x, y, z, w; };

typedef __attribute__((ext_vector_type(8))) short bf16x8;
typedef __attribute__((ext_vector_type(4))) float f32x4;

#define CH 32

__device__ __forceinline__ unsigned short f2bf(float f) {
    unsigned u = __float_as_uint(f);
    unsigned r = (u + 0x7fffu + ((u >> 16) & 1u)) >> 16;
    return (unsigned short)r;
}
__device__ __forceinline__ float bf2f(unsigned short u) {
    return __uint_as_float(((unsigned)u) << 16);
}
__device__ __forceinline__ float blo(unsigned u) { return __uint_as_float(u << 16); }
__device__ __forceinline__ float bhi(unsigned u) { return __uint_as_float(u & 0xffff0000u); }

// ---------------- pack B fragments: Bp[((t*4+s)*64+lane)*8+i] ----------------
__global__ __launch_bounds__(256) void k_bpack(
    const float* __restrict__ Wq, const float* __restrict__ Wk, const float* __restrict__ Wv,
    const float* __restrict__ compW, const float* __restrict__ We,
    unsigned short* __restrict__ Bp)
{
    int gid = blockIdx.x * 256 + threadIdx.x;
    if (gid >= 21 * 2048) return;                 // 43008
    int i = gid & 7, lane = (gid >> 3) & 63, s = (gid >> 9) & 3, t = gid >> 11;
    int col = t * 16 + (lane & 15);
    int k = s * 32 + ((lane >> 4) << 3) + i;
    float v;
    if (col < 64)        v = Wq[col * 128 + k];
    else if (col < 128)  v = Wk[(col - 64) * 128 + k];
    else if (col < 192)  v = Wv[(col - 128) * 128 + k];
    else if (col < 200)  v = compW[(col - 192) * 256 + k];
    else if (col < 208)  v = compW[(col - 200) * 256 + 128 + k];
    else {
        int hd = col - 208, h = hd >> 4, d = hd & 15;
        v = 0.f;
        #pragma unroll
        for (int c = 0; c < 8; c++)
            v += Wk[(h * 8 + c) * 128 + k] * We[(h * 8 + c) * 16 + d];
    }
    Bp[gid] = f2bf(v);
}

__device__ __forceinline__ bf16x8 ld_bf8(const float* p) {
    float4 a = ((const float4*)p)[0], b = ((const float4*)p)[1];
    bf16x8 r;
    r[0] = (short)f2bf(a.x); r[1] = (short)f2bf(a.y);
    r[2] = (short)f2bf(a.z); r[3] = (short)f2bf(a.w);
    r[4] = (short)f2bf(b.x); r[5] = (short)f2bf(b.y);
    r[6] = (short)f2bf(b.z); r[7] = (short)f2bf(b.w);
    return r;
}

// ---------------- MFMA projection GEMM -> q (separate) + interleaved record + bn ----------
__global__ __launch_bounds__(256) void k_gemm(
    const float* __restrict__ x, const unsigned short* __restrict__ Bp,
    const float* __restrict__ compb,
    float* __restrict__ q, unsigned short* __restrict__ rec,
    float* __restrict__ bnArr, int N)
{
    const int tid = threadIdx.x, w = tid >> 6, lane = tid & 63;
    const int half = lane >> 4;                   // 0..3
    const int c0 = lane & 15;
    int row_a = blockIdx.x * 64 + w * 16 + c0;
    int ra = min(row_a, N - 1);
    const float* xr = x + (size_t)ra * 128 + half * 8;
    bf16x8 a0 = ld_bf8(xr +  0);
    bf16x8 a1 = ld_bf8(xr + 32);
    bf16x8 a2 = ld_bf8(xr + 64);
    bf16x8 a3 = ld_bf8(xr + 96);
    const int rbase = blockIdx.x * 64 + w * 16 + half * 4;
    const float cbv = compb[c0 & 7];

    for (int t = 0; t < 21; t++) {
        f32x4 acc = {0.f, 0.f, 0.f, 0.f};
        const bf16x8* bp = (const bf16x8*)(Bp + (size_t)((t * 4) * 64 + lane) * 8);
        acc = __builtin_amdgcn_mfma_f32_16x16x32_bf16(a0, bp[0],   acc, 0, 0, 0);
        acc = __builtin_amdgcn_mfma_f32_16x16x32_bf16(a1, bp[64],  acc, 0, 0, 0);
        acc = __builtin_amdgcn_mfma_f32_16x16x32_bf16(a2, bp[128], acc, 0, 0, 0);
        acc = __builtin_amdgcn_mfma_f32_16x16x32_bf16(a3, bp[192], acc, 0, 0, 0);
        #pragma unroll
        for (int r = 0; r < 4; r++) {
            int rr = rbase + r;
            if (rr >= N) continue;
            float vr = acc[r];
            unsigned short* recR = rec + (size_t)rr * 320;
            if (t < 4)        q[(size_t)rr * 64 + t * 16 + c0] = vr * 0.35355339059327373f;
            else if (t < 8)   recR[(t - 4) * 16 + c0] = f2bf(vr);            // kb  (bytes 0-127)
            else if (t < 12)  recR[192 + (t - 8) * 16 + c0] = f2bf(vr);      // vb  (bytes 384-511)
            else if (t == 12) {
                if (c0 < 8) ((float*)(recR + 304))[c0] = vr;                 // an  (bytes 608-639)
                else        bnArr[(size_t)rr * 8 + (c0 - 8)] = vr + cbv;     // bn (+comp_b)
            }
            else              recR[64 + (t - 13) * 16 + c0] = f2bf(vr);      // Gb  (bytes 128-383)
        }
    }
}

// ---------------- tpn (ddof=1) -> int8 (scale 12) into record, one wave per node ----------
__global__ __launch_bounds__(256) void k_tpn(const float* __restrict__ tp,
                                             unsigned short* __restrict__ rec, int N)
{
    int wave = threadIdx.x >> 6;
    int lane = threadIdx.x & 63;
    int n = blockIdx.x * 4 + wave;
    if (n >= N) return;
    const float* row = tp + (size_t)n * 96;
    float v0 = row[lane];
    float v1 = (lane < 32) ? row[64 + lane] : 0.f;
    float s = v0 + v1, ss = v0 * v0 + v1 * v1;
    #pragma unroll
    for (int m = 1; m < 64; m <<= 1) { s += __shfl_xor(s, m); ss += __shfl_xor(ss, m); }
    float mean = s * (1.f / 96.f);
    float var = (ss - 96.f * mean * mean) * (1.f / 95.f);
    var = fmaxf(var, 0.f);
    float inv = 12.f / (sqrtf(var) + 1e-8f);      // scale 12 folded
    if (lane < 24) {
        float4 v = ((const float4*)row)[lane];
        int q0 = (int)rintf(fminf(fmaxf((v.x - mean) * inv, -127.f), 127.f));
        int q1 = (int)rintf(fminf(fmaxf((v.y - mean) * inv, -127.f), 127.f));
        int q2 = (int)rintf(fminf(fmaxf((v.z - mean) * inv, -127.f), 127.f));
        int q3 = (int)rintf(fminf(fmaxf((v.w - mean) * inv, -127.f), 127.f));
        unsigned pk = (q0 & 255) | ((q1 & 255) << 8) | ((q2 & 255) << 16) | ((q3 & 255) << 24);
        *((unsigned*)(rec + (size_t)n * 320 + 256) + lane) = pk;   // bytes 512-607
    }
}

// ---------------- CSR build: histogram(+rank) / 3-stage scan / atomic-free scatter ----------
__global__ __launch_bounds__(256) void k_hist(const int* __restrict__ ei,
                                              int* __restrict__ deg,
                                              int* __restrict__ rnk, int E0, int N)
{
    int e = blockIdx.x * 256 + threadIdx.x;
    int E = E0 + N;
    if (e >= E) return;
    int dst = (e < E0) ? ei[E0 + e] : (e - E0);
    rnk[e] = atomicAdd(&deg[dst], 1);
}

__global__ __launch_bounds__(256) void k_scanA(const int* __restrict__ deg,
                                               int* __restrict__ bsum, int N)
{
    __shared__ int sm[256];
    int i = blockIdx.x * 256 + threadIdx.x;
    sm[threadIdx.x] = (i < N) ? deg[i] : 0;
    __syncthreads();
    for (int off = 128; off > 0; off >>= 1) {
        if (threadIdx.x < off) sm[threadIdx.x] += sm[threadIdx.x + off];
        __syncthreads();
    }
    if (threadIdx.x == 0) bsum[blockIdx.x] = sm[0];
}

__global__ __launch_bounds__(256) void k_scanB(int* __restrict__ bsum, int NB)
{
    __shared__ int sm[256];
    int t = threadIdx.x;
    sm[t] = (t < NB) ? bsum[t] : 0;
    __syncthreads();
    for (int off = 1; off < 256; off <<= 1) {
        int v = (t >= off) ? sm[t - off] : 0;
        __syncthreads();
        sm[t] += v;
        __syncthreads();
    }
    if (t < NB) bsum[t] = (t == 0) ? 0 : sm[t - 1];
}

__global__ __launch_bounds__(256) void k_scanC(const int* __restrict__ deg,
                                               const int* __restrict__ bsum,
                                               int* __restrict__ row, int N)
{
    __shared__ int sm[256];
    int b = blockIdx.x, t = threadIdx.x, i = b * 256 + t;
    int v = (i < N) ? deg[i] : 0;
    sm[t] = v;
    __syncthreads();
    for (int off = 1; off < 256; off <<= 1) {
        int u = (t >= off) ? sm[t - off] : 0;
        __syncthreads();
        sm[t] += u;
        __syncthreads();
    }
    int excl = bsum[b] + sm[t] - v;
    if (i < N) {
        row[i] = excl;
        if (i == N - 1) row[N] = excl + v;
    }
}

__global__ __launch_bounds__(256) void k_scatter(const int* __restrict__ ei,
                                                 const int* __restrict__ row,
                                                 const int* __restrict__ rnk,
                                                 int2* __restrict__ csrd, int E0, int N)
{
    int e = blockIdx.x * 256 + threadIdx.x;
    int E = E0 + N;
    if (e >= E) return;
    int src, dst;
    if (e < E0) { src = ei[e]; dst = ei[E0 + e]; }
    else        { src = e - E0; dst = src; }
    int pos = row[dst] + rnk[e];
    csrd[pos] = make_int2(e, src);
}

// ---------------- fused per-node attention: chunked online softmax, all-register ----------
// one wave per node (4/block). lane = g*8+h: group g = edge slot, h = head / channel block.
// r11-proven inline-load structure; record is 640B/5 lines; tpn int8 with folded coeffs.
__global__ __launch_bounds__(256) void k_nodeattn(
    const int2* __restrict__ csrd, const int* __restrict__ row,
    const float* __restrict__ eattr,
    const float* __restrict__ q, const unsigned short* __restrict__ rec,
    const float* __restrict__ bnArr,
    const float* __restrict__ Wo, const float* __restrict__ bo,
    float* __restrict__ out, int E0, int N)
{
    const int tid = threadIdx.x;
    const int wave = tid >> 6, lane = tid & 63;
    const int n = blockIdx.x * 4 + wave;
    if (n >= N) return;

    const int beg = row[n], end = row[n + 1];
    const int h = lane & 7;           // head / channel block
    const int g = lane >> 3;          // edge slot
    const int koff = h * 8;           // record offsets (ushort units)
    const int goff = 64 + h * 16;
    const int voff = 192 + h * 8;

    // hoisted dst-side data (per head h)
    const unsigned short* recN = rec + (size_t)n * 320;
    const float4* qp = (const float4*)(q + (size_t)n * 64 + h * 8);
    const float4 qd0 = qp[0], qd1 = qp[1];
    const float bnh = bnArr[(size_t)n * 8 + h];
    // dst tpn int8 -> floats with corr coeff folded: -0.25/(96*144)
    float tdf[12];
    {
        const unsigned* tdq = (const unsigned*)(recN + 256) + h * 3;
        unsigned w0 = tdq[0], w1 = tdq[1], w2 = tdq[2];
        const float CC = -0.25f / (96.f * 144.f);
        tdf[0] = (float)((int)(w0 << 24) >> 24) * CC; tdf[1] = (float)((int)(w0 << 16) >> 24) * CC;
        tdf[2] = (float)((int)(w0 <<  8) >> 24) * CC; tdf[3] = (float)((int)w0 >> 24) * CC;
        tdf[4] = (float)((int)(w1 << 24) >> 24) * CC; tdf[5] = (float)((int)(w1 << 16) >> 24) * CC;
        tdf[6] = (float)((int)(w1 <<  8) >> 24) * CC; tdf[7] = (float)((int)w1 >> 24) * CC;
        tdf[8] = (float)((int)(w2 << 24) >> 24) * CC; tdf[9] = (float)((int)(w2 << 16) >> 24) * CC;
        tdf[10] = (float)((int)(w2 << 8) >> 24) * CC; tdf[11] = (float)((int)w2 >> 24) * CC;
    }

    float m_reg = -1e30f, dsum = 0.f;
    float acc[8];
    #pragma unroll
    for (int c = 0; c < 8; c++) acc[c] = 0.f;

    for (int cbeg = beg; cbeg < end; cbeg += CH) {
        const int cnt = min(CH, end - cbeg);

        float av[4];
        uint4 vu[4];
        // ---- phase L: logits + vb prefetch for this chunk (registers only) ----
        #pragma unroll
        for (int j = 0; j < 4; j++) {
            av[j] = -1e30f;
            vu[j] = make_uint4(0u, 0u, 0u, 0u);
            int eo = g + 8 * j;
            if (eo < cnt) {
                int2 es = csrd[cbeg + eo];
                const int e = es.x, s = es.y;
                const unsigned short* recS = rec + (size_t)s * 320;

                vu[j] = *(const uint4*)(recS + voff);   // prefetch V

                const US4* kp = (const US4*)(recS + koff);
                US4 k0 = kp[0], k1 = kp[1];
                float qk = qd0.x*bf2f(k0.x) + qd0.y*bf2f(k0.y) + qd0.z*bf2f(k0.z) + qd0.w*bf2f(k0.w)
                         + qd1.x*bf2f(k1.x) + qd1.y*bf2f(k1.y) + qd1.z*bf2f(k1.z) + qd1.w*bf2f(k1.w);

                const uint4* gp = (const uint4*)(recS + goff);
                uint4 g0 = gp[0], g1 = gp[1];
                int ec = (e < E0) ? e : 0;
                const float4* ep4 = (const float4*)(eattr + (size_t)ec * 16);
                float4 e0 = ep4[0], e1 = ep4[1], e2 = ep4[2], e3 = ep4[3];
                if (e >= E0) {
                    e0 = make_float4(1.f, 1.f, 1.f, 1.f); e1 = e0; e2 = e0; e3 = e0;
                }
                float efk = e0.x*blo(g0.x) + e0.y*bhi(g0.x) + e0.z*blo(g0.y) + e0.w*bhi(g0.y)
                          + e1.x*blo(g0.z) + e1.y*bhi(g0.z) + e1.z*blo(g0.w) + e1.w*bhi(g0.w)
                          + e2.x*blo(g1.x) + e2.y*bhi(g1.x) + e2.z*blo(g1.y) + e2.w*bhi(g1.y)
                          + e3.x*blo(g1.z) + e3.y*bhi(g1.z) + e3.z*blo(g1.w) + e3.w*bhi(g1.w);

                float tv = ((const float*)(recS + 304))[h] + bnh;
                float ex = __expf(2.f * tv);
                float tn = 1.f - 2.f / (ex + 1.f);

                const unsigned* tsq = (const unsigned*)(recS + 256) + h * 3;
                unsigned x0 = tsq[0], x1 = tsq[1], x2 = tsq[2];
                float pc =
                    (float)((int)(x0 << 24) >> 24) * tdf[0] + (float)((int)(x0 << 16) >> 24) * tdf[1]
                  + (float)((int)(x0 <<  8) >> 24) * tdf[2] + (float)((int)x0 >> 24) * tdf[3]
                  + (float)((int)(x1 << 24) >> 24) * tdf[4] + (float)((int)(x1 << 16) >> 24) * tdf[5]
                  + (float)((int)(x1 <<  8) >> 24) * tdf[6] + (float)((int)x1 >> 24) * tdf[7]
                  + (float)((int)(x2 << 24) >> 24) * tdf[8] + (float)((int)(x2 << 16) >> 24) * tdf[9]
                  + (float)((int)(x2 <<  8) >> 24) * tdf[10] + (float)((int)x2 >> 24) * tdf[11];
                float cv = pc + tn * (-0.25f / 8.f);    // corr coeff pre-folded in tdf
                cv += __shfl_xor(cv, 1); cv += __shfl_xor(cv, 2); cv += __shfl_xor(cv, 4);

                float a = qk + efk + cv;
                av[j] = fmaxf(a, 0.2f * a);            // leaky relu
            }
        }

        // ---- chunk max per head (across groups: lane bits 3-5) ----
        float mloc = fmaxf(fmaxf(av[0], av[1]), fmaxf(av[2], av[3]));
        mloc = fmaxf(mloc, __shfl_xor(mloc, 8));
        mloc = fmaxf(mloc, __shfl_xor(mloc, 16));
        mloc = fmaxf(mloc, __shfl_xor(mloc, 32));

        // ---- online merge + accumulate (all register) ----
        float mn = fmaxf(m_reg, mloc);
        float sc = __expf(m_reg - mn);
        m_reg = mn;
        dsum *= sc;
        #pragma unroll
        for (int c = 0; c < 8; c++) acc[c] *= sc;

        #pragma unroll
        for (int j = 0; j < 4; j++) {
            float p = __expf(av[j] - mn);              // 0 for inactive slots
            dsum += p;
            acc[0] += p * blo(vu[j].x); acc[1] += p * bhi(vu[j].x);
            acc[2] += p * blo(vu[j].y); acc[3] += p * bhi(vu[j].y);
            acc[4] += p * blo(vu[j].z); acc[5] += p * bhi(vu[j].z);
            acc[6] += p * blo(vu[j].w); acc[7] += p * bhi(vu[j].w);
        }
    }

    // ---- merge slots (bits 3-5): per-head denom + channel sums ----
    dsum += __shfl_xor(dsum, 8); dsum += __shfl_xor(dsum, 16); dsum += __shfl_xor(dsum, 32);
    #pragma unroll
    for (int c = 0; c < 8; c++) {
        acc[c] += __shfl_xor(acc[c], 8);
        acc[c] += __shfl_xor(acc[c], 16);
        acc[c] += __shfl_xor(acc[c], 32);
    }
    float inv = 1.f / (dsum + 1e-16f);

    // ---- fused Wo projection: lane holds channels h*8..h*8+7 ----
    float po[8];
    #pragma unroll
    for (int cp8 = 0; cp8 < 8; cp8++) {
        const float4* wr = (const float4*)(Wo + cp8 * 64 + h * 8);
        float4 w0 = wr[0], w1 = wr[1];
        po[cp8] = inv * (acc[0]*w0.x + acc[1]*w0.y + acc[2]*w0.z + acc[3]*w0.w
                       + acc[4]*w1.x + acc[5]*w1.y + acc[6]*w1.z + acc[7]*w1.w);
    }
    #pragma unroll
    for (int cp8 = 0; cp8 < 8; cp8++) {
        po[cp8] += __shfl_xor(po[cp8], 1);
        po[cp8] += __shfl_xor(po[cp8], 2);
        po[cp8] += __shfl_xor(po[cp8], 4);
    }
    if (lane < 8) out[(size_t)n * 8 + lane] = po[lane] + bo[lane];
}

extern "C" void kernel_launch(void* const* d_in, const int* in_sizes, int n_in,
                              void* d_out, int out_size, void* d_ws, size_t ws_size,
                              hipStream_t stream)
{
    const float* x     = (const float*)d_in[0];
    const int*   ei    = (const int*)d_in[1];
    const float* eattr = (const float*)d_in[2];
    const float* tp    = (const float*)d_in[3];
    const float* Wq    = (const float*)d_in[4];
    const float* Wk    = (const float*)d_in[5];
    const float* Wv    = (const float*)d_in[6];
    const float* We    = (const float*)d_in[7];
    const float* compW = (const float*)d_in[8];
    const float* compb = (const float*)d_in[9];
    const float* Wo    = (const float*)d_in[10];
    const float* bo    = (const float*)d_in[11];
    float* out = (float*)d_out;

    const int N  = in_sizes[0] / 128;
    const int E0 = in_sizes[1] / 2;
    const int E  = E0 + N;
    const int NB = (N + 255) / 256;

    float* ws = (float*)d_ws;
    size_t off = 0;
    unsigned short* rec = (unsigned short*)(ws + off); off += (size_t)N * 160;   // N x 640B records
    float* q  = ws + off; off += (size_t)N * 64;
    float* bnArr = ws + off; off += (size_t)N * 8;
    int* deg    = (int*)(ws + off); off += N;
    int* bsum   = (int*)(ws + off); off += 256;
    int* rowp   = (int*)(ws + off); off += N + 4;
    unsigned short* Bp = (unsigned short*)(ws + off); off += 21504;              // 43008 ushort
    int2* csrd  = (int2*)(ws + off); off += (size_t)E * 2;
    int* rnk    = (int*)(ws + off); off += E;

    hipMemsetAsync(deg, 0, (size_t)N * sizeof(int), stream);

    k_hist<<<(E + 255) / 256, 256, 0, stream>>>(ei, deg, rnk, E0, N);
    k_scanA<<<NB, 256, 0, stream>>>(deg, bsum, N);
    k_scanB<<<1, 256, 0, stream>>>(bsum, NB);
    k_scanC<<<NB, 256, 0, stream>>>(deg, bsum, rowp, N);
    k_scatter<<<(E + 255) / 256, 256, 0, stream>>>(ei, rowp, rnk, csrd, E0, N);

    k_bpack<<<(21 * 2048 + 255) / 256, 256, 0, stream>>>(Wq, Wk, Wv, compW, We, Bp);
    k_gemm<<<(N + 63) / 64, 256, 0, stream>>>(x, Bp, compb, q, rec, bnArr, N);
    k_tpn<<<(N + 3) / 4, 256, 0, stream>>>(tp, rec, N);

    k_nodeattn<<<(N + 3) / 4, 256, 0, stream>>>(csrd, rowp, eattr, q, rec, bnArr,
                                                Wo, bo, out, E0, N);
}

// Round 14
// 200.951 us; speedup vs baseline: 1.2847x; 1.0313x over previous
//
#include <hip/hip_runtime.h>
#include <math.h>

// N=50000 nodes, E0=800000 edges (+N self loops), IN=128, H=8, C=8 (HC=64), ED=16, T=96
// Node data: ONE interleaved 640B record per node (exactly 5 cache lines):
//   bytes: kb 0-127 | Gb 128-383 | vb 384-511 | tpn(int8, scale 12) 512-607 | an(f32) 608-639
//   (bn lives in a separate dst-side array; q separate f32, pre-scaled 1/sqrt8)
// Projections via one MFMA GEMM x[N][128] @ B[128][336]; edge phase fused per-node
// (chunked online softmax, all-register; corr via v_dot4_i32_i8 on packed int8).

struct __align__(8) US4 { unsigned short x, y, z, w; };

typedef __attribute__((ext_vector_type(8))) short bf16x8;
typedef __attribute__((ext_vector_type(4))) float f32x4;

#define CH 32

__device__ __forceinline__ unsigned short f2bf(float f) {
    unsigned u = __float_as_uint(f);
    unsigned r = (u + 0x7fffu + ((u >> 16) & 1u)) >> 16;
    return (unsigned short)r;
}
__device__ __forceinline__ float bf2f(unsigned short u) {
    return __uint_as_float(((unsigned)u) << 16);
}
__device__ __forceinline__ float blo(unsigned u) { return __uint_as_float(u << 16); }
__device__ __forceinline__ float bhi(unsigned u) { return __uint_as_float(u & 0xffff0000u); }

// ---------------- pack B fragments: Bp[((t*4+s)*64+lane)*8+i] ----------------
__global__ __launch_bounds__(256) void k_bpack(
    const float* __restrict__ Wq, const float* __restrict__ Wk, const float* __restrict__ Wv,
    const float* __restrict__ compW, const float* __restrict__ We,
    unsigned short* __restrict__ Bp)
{
    int gid = blockIdx.x * 256 + threadIdx.x;
    if (gid >= 21 * 2048) return;                 // 43008
    int i = gid & 7, lane = (gid >> 3) & 63, s = (gid >> 9) & 3, t = gid >> 11;
    int col = t * 16 + (lane & 15);
    int k = s * 32 + ((lane >> 4) << 3) + i;
    float v;
    if (col < 64)        v = Wq[col * 128 + k];
    else if (col < 128)  v = Wk[(col - 64) * 128 + k];
    else if (col < 192)  v = Wv[(col - 128) * 128 + k];
    else if (col < 200)  v = compW[(col - 192) * 256 + k];
    else if (col < 208)  v = compW[(col - 200) * 256 + 128 + k];
    else {
        int hd = col - 208, h = hd >> 4, d = hd & 15;
        v = 0.f;
        #pragma unroll
        for (int c = 0; c < 8; c++)
            v += Wk[(h * 8 + c) * 128 + k] * We[(h * 8 + c) * 16 + d];
    }
    Bp[gid] = f2bf(v);
}

__device__ __forceinline__ bf16x8 ld_bf8(const float* p) {
    float4 a = ((const float4*)p)[0], b = ((const float4*)p)[1];
    bf16x8 r;
    r[0] = (short)f2bf(a.x); r[1] = (short)f2bf(a.y);
    r[2] = (short)f2bf(a.z); r[3] = (short)f2bf(a.w);
    r[4] = (short)f2bf(b.x); r[5] = (short)f2bf(b.y);
    r[6] = (short)f2bf(b.z); r[7] = (short)f2bf(b.w);
    return r;
}

// ---------------- MFMA projection GEMM -> q (separate) + interleaved record + bn ----------
__global__ __launch_bounds__(256) void k_gemm(
    const float* __restrict__ x, const unsigned short* __restrict__ Bp,
    const float* __restrict__ compb,
    float* __restrict__ q, unsigned short* __restrict__ rec,
    float* __restrict__ bnArr, int N)
{
    const int tid = threadIdx.x, w = tid >> 6, lane = tid & 63;
    const int half = lane >> 4;                   // 0..3
    const int c0 = lane & 15;
    int row_a = blockIdx.x * 64 + w * 16 + c0;
    int ra = min(row_a, N - 1);
    const float* xr = x + (size_t)ra * 128 + half * 8;
    bf16x8 a0 = ld_bf8(xr +  0);
    bf16x8 a1 = ld_bf8(xr + 32);
    bf16x8 a2 = ld_bf8(xr + 64);
    bf16x8 a3 = ld_bf8(xr + 96);
    const int rbase = blockIdx.x * 64 + w * 16 + half * 4;
    const float cbv = compb[c0 & 7];

    for (int t = 0; t < 21; t++) {
        f32x4 acc = {0.f, 0.f, 0.f, 0.f};
        const bf16x8* bp = (const bf16x8*)(Bp + (size_t)((t * 4) * 64 + lane) * 8);
        acc = __builtin_amdgcn_mfma_f32_16x16x32_bf16(a0, bp[0],   acc, 0, 0, 0);
        acc = __builtin_amdgcn_mfma_f32_16x16x32_bf16(a1, bp[64],  acc, 0, 0, 0);
        acc = __builtin_amdgcn_mfma_f32_16x16x32_bf16(a2, bp[128], acc, 0, 0, 0);
        acc = __builtin_amdgcn_mfma_f32_16x16x32_bf16(a3, bp[192], acc, 0, 0, 0);
        #pragma unroll
        for (int r = 0; r < 4; r++) {
            int rr = rbase + r;
            if (rr >= N) continue;
            float vr = acc[r];
            unsigned short* recR = rec + (size_t)rr * 320;
            if (t < 4)        q[(size_t)rr * 64 + t * 16 + c0] = vr * 0.35355339059327373f;
            else if (t < 8)   recR[(t - 4) * 16 + c0] = f2bf(vr);            // kb  (bytes 0-127)
            else if (t < 12)  recR[192 + (t - 8) * 16 + c0] = f2bf(vr);      // vb  (bytes 384-511)
            else if (t == 12) {
                if (c0 < 8) ((float*)(recR + 304))[c0] = vr;                 // an  (bytes 608-639)
                else        bnArr[(size_t)rr * 8 + (c0 - 8)] = vr + cbv;     // bn (+comp_b)
            }
            else              recR[64 + (t - 13) * 16 + c0] = f2bf(vr);      // Gb  (bytes 128-383)
        }
    }
}

// ---------------- tpn (ddof=1) -> int8 (scale 12) into record, one wave per node ----------
__global__ __launch_bounds__(256) void k_tpn(const float* __restrict__ tp,
                                             unsigned short* __restrict__ rec, int N)
{
    int wave = threadIdx.x >> 6;
    int lane = threadIdx.x & 63;
    int n = blockIdx.x * 4 + wave;
    if (n >= N) return;
    const float* row = tp + (size_t)n * 96;
    float v0 = row[lane];
    float v1 = (lane < 32) ? row[64 + lane] : 0.f;
    float s = v0 + v1, ss = v0 * v0 + v1 * v1;
    #pragma unroll
    for (int m = 1; m < 64; m <<= 1) { s += __shfl_xor(s, m); ss += __shfl_xor(ss, m); }
    float mean = s * (1.f / 96.f);
    float var = (ss - 96.f * mean * mean) * (1.f / 95.f);
    var = fmaxf(var, 0.f);
    float inv = 12.f / (sqrtf(var) + 1e-8f);      // scale 12 folded
    if (lane < 24) {
        float4 v = ((const float4*)row)[lane];
        int q0 = (int)rintf(fminf(fmaxf((v.x - mean) * inv, -127.f), 127.f));
        int q1 = (int)rintf(fminf(fmaxf((v.y - mean) * inv, -127.f), 127.f));
        int q2 = (int)rintf(fminf(fmaxf((v.z - mean) * inv, -127.f), 127.f));
        int q3 = (int)rintf(fminf(fmaxf((v.w - mean) * inv, -127.f), 127.f));
        unsigned pk = (q0 & 255) | ((q1 & 255) << 8) | ((q2 & 255) << 16) | ((q3 & 255) << 24);
        *((unsigned*)(rec + (size_t)n * 320 + 256) + lane) = pk;   // bytes 512-607
    }
}

// ---------------- CSR build: histogram(+rank) / 3-stage scan / atomic-free scatter ----------
__global__ __launch_bounds__(256) void k_hist(const int* __restrict__ ei,
                                              int* __restrict__ deg,
                                              int* __restrict__ rnk, int E0, int N)
{
    int e = blockIdx.x * 256 + threadIdx.x;
    int E = E0 + N;
    if (e >= E) return;
    int dst = (e < E0) ? ei[E0 + e] : (e - E0);
    rnk[e] = atomicAdd(&deg[dst], 1);
}

__global__ __launch_bounds__(256) void k_scanA(const int* __restrict__ deg,
                                               int* __restrict__ bsum, int N)
{
    __shared__ int sm[256];
    int i = blockIdx.x * 256 + threadIdx.x;
    sm[threadIdx.x] = (i < N) ? deg[i] : 0;
    __syncthreads();
    for (int off = 128; off > 0; off >>= 1) {
        if (threadIdx.x < off) sm[threadIdx.x] += sm[threadIdx.x + off];
        __syncthreads();
    }
    if (threadIdx.x == 0) bsum[blockIdx.x] = sm[0];
}

__global__ __launch_bounds__(256) void k_scanB(int* __restrict__ bsum, int NB)
{
    __shared__ int sm[256];
    int t = threadIdx.x;
    sm[t] = (t < NB) ? bsum[t] : 0;
    __syncthreads();
    for (int off = 1; off < 256; off <<= 1) {
        int v = (t >= off) ? sm[t - off] : 0;
        __syncthreads();
        sm[t] += v;
        __syncthreads();
    }
    if (t < NB) bsum[t] = (t == 0) ? 0 : sm[t - 1];
}

__global__ __launch_bounds__(256) void k_scanC(const int* __restrict__ deg,
                                               const int* __restrict__ bsum,
                                               int* __restrict__ row, int N)
{
    __shared__ int sm[256];
    int b = blockIdx.x, t = threadIdx.x, i = b * 256 + t;
    int v = (i < N) ? deg[i] : 0;
    sm[t] = v;
    __syncthreads();
    for (int off = 1; off < 256; off <<= 1) {
        int u = (t >= off) ? sm[t - off] : 0;
        __syncthreads();
        sm[t] += u;
        __syncthreads();
    }
    int excl = bsum[b] + sm[t] - v;
    if (i < N) {
        row[i] = excl;
        if (i == N - 1) row[N] = excl + v;
    }
}

__global__ __launch_bounds__(256) void k_scatter(const int* __restrict__ ei,
                                                 const int* __restrict__ row,
                                                 const int* __restrict__ rnk,
                                                 int2* __restrict__ csrd, int E0, int N)
{
    int e = blockIdx.x * 256 + threadIdx.x;
    int E = E0 + N;
    if (e >= E) return;
    int src, dst;
    if (e < E0) { src = ei[e]; dst = ei[E0 + e]; }
    else        { src = e - E0; dst = src; }
    int pos = row[dst] + rnk[e];
    csrd[pos] = make_int2(e, src);
}

// ---------------- fused per-node attention: chunked online softmax, all-register ----------
// one wave per node (4/block). lane = g*8+h: group g = edge slot, h = head / channel block.
// corr = v_dot4_i32_i8 chain on packed int8 tpn (exact int arithmetic), coeff folded once.
__global__ __launch_bounds__(256) void k_nodeattn(
    const int2* __restrict__ csrd, const int* __restrict__ row,
    const float* __restrict__ eattr,
    const float* __restrict__ q, const unsigned short* __restrict__ rec,
    const float* __restrict__ bnArr,
    const float* __restrict__ Wo, const float* __restrict__ bo,
    float* __restrict__ out, int E0, int N)
{
    const int tid = threadIdx.x;
    const int wave = tid >> 6, lane = tid & 63;
    const int n = blockIdx.x * 4 + wave;
    if (n >= N) return;

    const int beg = row[n], end = row[n + 1];
    const int h = lane & 7;           // head / channel block
    const int g = lane >> 3;          // edge slot
    const int koff = h * 8;           // record offsets (ushort units)
    const int goff = 64 + h * 16;
    const int voff = 192 + h * 8;

    // hoisted dst-side data (per head h)
    const unsigned short* recN = rec + (size_t)n * 320;
    const float4* qp = (const float4*)(q + (size_t)n * 64 + h * 8);
    const float4 qd0 = qp[0], qd1 = qp[1];
    const float bnh = bnArr[(size_t)n * 8 + h];
    // dst tpn: raw packed int8 words (sdot4 operands)
    const unsigned* tdq = (const unsigned*)(recN + 256) + h * 3;
    const int y0 = (int)tdq[0], y1 = (int)tdq[1], y2 = (int)tdq[2];
    const float CC = -0.25f / (96.f * 144.f);   // corr coeff (int dot -> logit)

    float m_reg = -1e30f, dsum = 0.f;
    float acc[8];
    #pragma unroll
    for (int c = 0; c < 8; c++) acc[c] = 0.f;

    for (int cbeg = beg; cbeg < end; cbeg += CH) {
        const int cnt = min(CH, end - cbeg);

        float av[4];
        uint4 vu[4];
        // ---- phase L: logits + vb prefetch for this chunk (registers only) ----
        #pragma unroll
        for (int j = 0; j < 4; j++) {
            av[j] = -1e30f;
            vu[j] = make_uint4(0u, 0u, 0u, 0u);
            int eo = g + 8 * j;
            if (eo < cnt) {
                int2 es = csrd[cbeg + eo];
                const int e = es.x, s = es.y;
                const unsigned short* recS = rec + (size_t)s * 320;

                vu[j] = *(const uint4*)(recS + voff);   // prefetch V

                const US4* kp = (const US4*)(recS + koff);
                US4 k0 = kp[0], k1 = kp[1];
                float qk = qd0.x*bf2f(k0.x) + qd0.y*bf2f(k0.y) + qd0.z*bf2f(k0.z) + qd0.w*bf2f(k0.w)
                         + qd1.x*bf2f(k1.x) + qd1.y*bf2f(k1.y) + qd1.z*bf2f(k1.z) + qd1.w*bf2f(k1.w);

                const uint4* gp = (const uint4*)(recS + goff);
                uint4 g0 = gp[0], g1 = gp[1];
                int ec = (e < E0) ? e : 0;
                const float4* ep4 = (const float4*)(eattr + (size_t)ec * 16);
                float4 e0 = ep4[0], e1 = ep4[1], e2 = ep4[2], e3 = ep4[3];
                if (e >= E0) {
                    e0 = make_float4(1.f, 1.f, 1.f, 1.f); e1 = e0; e2 = e0; e3 = e0;
                }
                float efk = e0.x*blo(g0.x) + e0.y*bhi(g0.x) + e0.z*blo(g0.y) + e0.w*bhi(g0.y)
                          + e1.x*blo(g0.z) + e1.y*bhi(g0.z) + e1.z*blo(g0.w) + e1.w*bhi(g0.w)
                          + e2.x*blo(g1.x) + e2.y*bhi(g1.x) + e2.z*blo(g1.y) + e2.w*bhi(g1.y)
                          + e3.x*blo(g1.z) + e3.y*bhi(g1.z) + e3.z*blo(g1.w) + e3.w*bhi(g1.w);

                float tv = ((const float*)(recS + 304))[h] + bnh;
                float ex = __expf(2.f * tv);
                float tn = 1.f - 2.f / (ex + 1.f);

                const unsigned* tsq = (const unsigned*)(recS + 256) + h * 3;
                unsigned x0 = tsq[0], x1 = tsq[1], x2 = tsq[2];
#if __has_builtin(__builtin_amdgcn_sdot4)
                int di = __builtin_amdgcn_sdot4((int)x0, y0, 0, false);
                di = __builtin_amdgcn_sdot4((int)x1, y1, di, false);
                di = __builtin_amdgcn_sdot4((int)x2, y2, di, false);
                float pc = (float)di * CC;
#else
                float pc =
                    (float)((int)(x0 << 24) >> 24) * (float)((int)(y0 << 24) >> 24)
                  + (float)((int)(x0 << 16) >> 24) * (float)((int)(y0 << 16) >> 24)
                  + (float)((int)(x0 <<  8) >> 24) * (float)((int)(y0 <<  8) >> 24)
                  + (float)((int)x0 >> 24)         * (float)((int)y0 >> 24)
                  + (float)((int)(x1 << 24) >> 24) * (float)((int)(y1 << 24) >> 24)
                  + (float)((int)(x1 << 16) >> 24) * (float)((int)(y1 << 16) >> 24)
                  + (float)((int)(x1 <<  8) >> 24) * (float)((int)(y1 <<  8) >> 24)
                  + (float)((int)x1 >> 24)         * (float)((int)y1 >> 24)
                  + (float)((int)(x2 << 24) >> 24) * (float)((int)(y2 << 24) >> 24)
                  + (float)((int)(x2 << 16) >> 24) * (float)((int)(y2 << 16) >> 24)
                  + (float)((int)(x2 <<  8) >> 24) * (float)((int)(y2 <<  8) >> 24)
                  + (float)((int)x2 >> 24)         * (float)((int)y2 >> 24);
                pc *= CC;
#endif
                float cv = pc + tn * (-0.25f / 8.f);
                cv += __shfl_xor(cv, 1); cv += __shfl_xor(cv, 2); cv += __shfl_xor(cv, 4);

                float a = qk + efk + cv;
                av[j] = fmaxf(a, 0.2f * a);            // leaky relu
            }
        }

        // ---- chunk max per head (across groups: lane bits 3-5) ----
        float mloc = fmaxf(fmaxf(av[0], av[1]), fmaxf(av[2], av[3]));
        mloc = fmaxf(mloc, __shfl_xor(mloc, 8));
        mloc = fmaxf(mloc, __shfl_xor(mloc, 16));
        mloc = fmaxf(mloc, __shfl_xor(mloc, 32));

        // ---- online merge + accumulate (all register) ----
        float mn = fmaxf(m_reg, mloc);
        float sc = __expf(m_reg - mn);
        m_reg = mn;
        dsum *= sc;
        #pragma unroll
        for (int c = 0; c < 8; c++) acc[c] *= sc;

        #pragma unroll
        for (int j = 0; j < 4; j++) {
            float p = __expf(av[j] - mn);              // 0 for inactive slots
            dsum += p;
            acc[0] += p * blo(vu[j].x); acc[1] += p * bhi(vu[j].x);
            acc[2] += p * blo(vu[j].y); acc[3] += p * bhi(vu[j].y);
            acc[4] += p * blo(vu[j].z); acc[5] += p * bhi(vu[j].z);
            acc[6] += p * blo(vu[j].w); acc[7] += p * bhi(vu[j].w);
        }
    }

    // ---- merge slots (bits 3-5): per-head denom + channel sums ----
    dsum += __shfl_xor(dsum, 8); dsum += __shfl_xor(dsum, 16); dsum += __shfl_xor(dsum, 32);
    #pragma unroll
    for (int c = 0; c < 8; c++) {
        acc[c] += __shfl_xor(acc[c], 8);
        acc[c] += __shfl_xor(acc[c], 16);
        acc[c] += __shfl_xor(acc[c], 32);
    }
    float inv = 1.f / (dsum + 1e-16f);

    // ---- fused Wo projection: lane holds channels h*8..h*8+7 ----
    float po[8];
    #pragma unroll
    for (int cp8 = 0; cp8 < 8; cp8++) {
        const float4* wr = (const float4*)(Wo + cp8 * 64 + h * 8);
        float4 w0 = wr[0], w1 = wr[1];
        po[cp8] = inv * (acc[0]*w0.x + acc[1]*w0.y + acc[2]*w0.z + acc[3]*w0.w
                       + acc[4]*w1.x + acc[5]*w1.y + acc[6]*w1.z + acc[7]*w1.w);
    }
    #pragma unroll
    for (int cp8 = 0; cp8 < 8; cp8++) {
        po[cp8] += __shfl_xor(po[cp8], 1);
        po[cp8] += __shfl_xor(po[cp8], 2);
        po[cp8] += __shfl_xor(po[cp8], 4);
    }
    if (lane < 8) out[(size_t)n * 8 + lane] = po[lane] + bo[lane];
}

extern "C" void kernel_launch(void* const* d_in, const int* in_sizes, int n_in,
                              void* d_out, int out_size, void* d_ws, size_t ws_size,
                              hipStream_t stream)
{
    const float* x     = (const float*)d_in[0];
    const int*   ei    = (const int*)d_in[1];
    const float* eattr = (const float*)d_in[2];
    const float* tp    = (const float*)d_in[3];
    const float* Wq    = (const float*)d_in[4];
    const float* Wk    = (const float*)d_in[5];
    const float* Wv    = (const float*)d_in[6];
    const float* We    = (const float*)d_in[7];
    const float* compW = (const float*)d_in[8];
    const float* compb = (const float*)d_in[9];
    const float* Wo    = (const float*)d_in[10];
    const float* bo    = (const float*)d_in[11];
    float* out = (float*)d_out;

    const int N  = in_sizes[0] / 128;
    const int E0 = in_sizes[1] / 2;
    const int E  = E0 + N;
    const int NB = (N + 255) / 256;

    float* ws = (float*)d_ws;
    size_t off = 0;
    unsigned short* rec = (unsigned short*)(ws + off); off += (size_t)N * 160;   // N x 640B records
    float* q  = ws + off; off += (size_t)N * 64;
    float* bnArr = ws + off; off += (size_t)N * 8;
    int* deg    = (int*)(ws + off); off += N;
    int* bsum   = (int*)(ws + off); off += 256;
    int* rowp   = (int*)(ws + off); off += N + 4;
    unsigned short* Bp = (unsigned short*)(ws + off); off += 21504;              // 43008 ushort
    int2* csrd  = (int2*)(ws + off); off += (size_t)E * 2;
    int* rnk    = (int*)(ws + off); off += E;

    hipMemsetAsync(deg, 0, (size_t)N * sizeof(int), stream);

    k_hist<<<(E + 255) / 256, 256, 0, stream>>>(ei, deg, rnk, E0, N);
    k_scanA<<<NB, 256, 0, stream>>>(deg, bsum, N);
    k_scanB<<<1, 256, 0, stream>>>(bsum, NB);
    k_scanC<<<NB, 256, 0, stream>>>(deg, bsum, rowp, N);
    k_scatter<<<(E + 255) / 256, 256, 0, stream>>>(ei, rowp, rnk, csrd, E0, N);

    k_bpack<<<(21 * 2048 + 255) / 256, 256, 0, stream>>>(Wq, Wk, Wv, compW, We, Bp);
    k_gemm<<<(N + 63) / 64, 256, 0, stream>>>(x, Bp, compb, q, rec, bnArr, N);
    k_tpn<<<(N + 3) / 4, 256, 0, stream>>>(tp, rec, N);

    k_nodeattn<<<(N + 3) / 4, 256, 0, stream>>>(csrd, rowp, eattr, q, rec, bnArr,
                                                Wo, bo, out, E0, N);
}